// Round 27
// baseline (108.104 us; speedup 1.0000x reference)
//
#include <hip/hip_runtime.h>

#define KLEN 1024
#define HOP 512
#define NW 511
#define NB 4
#define NC 16
#define NBINS 513
#define NSAMP 262144
#define MAPN (NC * KLEN)

// ws layout (bytes): map float4[MAPN] @0 | hann float[1024] @262144
#define WS_HANN 262144

// LDS dump layout: bin kk = k1 + 16*k2 -> addr = k1 + 17*k2 (<=2-way banks)
#define DIDX(kk) (((kk) & 15) + 17 * ((kk) >> 4))

#define CMULBF(ar,ai,br,bi,wr,wi) { float tr_=(ar)-(br), ti_=(ai)-(bi); \
    (ar)+=(br); (ai)+=(bi); (br)=tr_*(wr)-ti_*(wi); (bi)=tr_*(wi)+ti_*(wr); }
#define CMUL(xr,xi,yr,yi,or_,oi_) { (or_)=(xr)*(yr)-(xi)*(yi); (oi_)=(xr)*(yi)+(xi)*(yr); }

__global__ __launch_bounds__(256) void warpmap_kernel(
    const float* __restrict__ dlnf,
    float4* __restrict__ map, float* __restrict__ g_hann)
{
    const int c = blockIdx.x;
    const double TWO_PI = 6.283185307179586476925287;
    const double beta = 2.0 * (double)dlnf[c];
    const bool small = fabs(beta) < 1e-8;
    const double bs = small ? 1e-8 : beta;
    const double e2b = exp(2.0 * bs);
    const double t_mid = small ? 0.0 : (log(1.0 + 0.5 * (e2b - 1.0)) / bs - 1.0);

    for (int j = threadIdx.x; j < KLEN; j += 256) {
        double tau = 2.0 * (double)j / 1024.0 - 1.0;
        double ts, jac;
        if (small) { ts = tau; jac = 1.0; }
        else {
            ts = log(1.0 + (tau + 1.0) * 0.5 * (e2b - 1.0)) / bs - 1.0;
            jac = exp(-bs * (ts - t_mid));
        }
        double idxf = 512.0 * (ts + 1.0);
        int lo = (int)idxf;
        lo = lo < 0 ? 0 : (lo > 1022 ? 1022 : lo);
        map[c * KLEN + j] = make_float4(__int_as_float(lo),
                                        (float)(idxf - (double)lo),
                                        (float)jac, 0.0f);
    }
    if (c == 0) {
        for (int k = threadIdx.x; k < KLEN; k += 256)
            g_hann[k] = (float)(0.5 * (1.0 - cos(TWO_PI * (double)k / 1024.0)));
    }
}

__global__ __launch_bounds__(64, 4) void dechirp_regfft2_kernel(
    const float* __restrict__ x,
    const float4* __restrict__ map,
    const float4* __restrict__ g_hann4,
    float* __restrict__ out)
{
    __shared__ float wd[KLEN];
    __shared__ float dump0[17 * 64], dump1[17 * 64];

    const int lane = threadIdx.x;
    const int blin = blockIdx.x;            // (b*NW + w)*4 + pp
    const int pp   = blin & 3;              // two chirp-pairs per block
    const int w    = (blin >> 2) % NW;
    const int b    = blin / (4 * NW);
    const int cbase = 4 * pp;               // chirps cbase..cbase+3

    // Stage windowed frame (float4), wave-private block
    const float4* xrow4 = (const float4*)(x + (size_t)b * NSAMP + (size_t)w * HOP);
    float4* wd4 = (float4*)wd;
    #pragma unroll
    for (int t = 0; t < 4; ++t) {
        int k4 = lane + (t << 6);
        float4 xv = xrow4[k4];
        float4 hv = g_hann4[k4];
        wd4[k4] = make_float4(xv.x * hv.x, xv.y * hv.y, xv.z * hv.z, xv.w * hv.w);
    }
    __builtin_amdgcn_wave_barrier();

    // ---- Phase 1: resample 4 chirps into 2 complex streams
    float zr[2][16], zi[2][16];
    #pragma unroll
    for (int s = 0; s < 2; ++s) {
        const float4* mp0 = map + (cbase + 2 * s) * KLEN;
        const float4* mp1 = map + (cbase + 2 * s + 1) * KLEN;
        #pragma unroll
        for (int t = 0; t < 16; ++t) {
            int j = lane + (t << 6);
            float4 a = mp0[j];
            int   a0 = __float_as_int(a.x);
            zr[s][t] = (wd[a0] * (1.0f - a.y) + wd[a0 + 1] * a.y) * a.z;
            float4 bb = mp1[j];
            int   a1 = __float_as_int(bb.x);
            zi[s][t] = (wd[a1] * (1.0f - bb.y) + wd[a1 + 1] * bb.y) * bb.z;
        }
    }

    // ---- Phase 2: 16-point DIF FFT in registers, both streams interleaved
    {
        constexpr float W16R[8] = { 1.0f, 0.9238795325f, 0.7071067812f, 0.3826834324f,
                                    0.0f,-0.3826834324f,-0.7071067812f,-0.9238795325f };
        constexpr float W16I[8] = { 0.0f,-0.3826834324f,-0.7071067812f,-0.9238795325f,
                                   -1.0f,-0.9238795325f,-0.7071067812f,-0.3826834324f };
        constexpr float W8R[4]  = { 1.0f, 0.7071067812f, 0.0f,-0.7071067812f };
        constexpr float W8I[4]  = { 0.0f,-0.7071067812f,-1.0f,-0.7071067812f };
        #pragma unroll
        for (int j = 0; j < 8; ++j)
            #pragma unroll
            for (int s = 0; s < 2; ++s)
                CMULBF(zr[s][j],zi[s][j],zr[s][j+8],zi[s][j+8],W16R[j],W16I[j]);
        #pragma unroll
        for (int g = 0; g < 2; ++g)
            #pragma unroll
            for (int j = 0; j < 4; ++j)
                #pragma unroll
                for (int s = 0; s < 2; ++s)
                    CMULBF(zr[s][g*8+j],zi[s][g*8+j],zr[s][g*8+j+4],zi[s][g*8+j+4],W8R[j],W8I[j]);
        #pragma unroll
        for (int g = 0; g < 4; ++g)
            #pragma unroll
            for (int s = 0; s < 2; ++s) {
                CMULBF(zr[s][g*4],zi[s][g*4],zr[s][g*4+2],zi[s][g*4+2],1.0f,0.0f);
                CMULBF(zr[s][g*4+1],zi[s][g*4+1],zr[s][g*4+3],zi[s][g*4+3],0.0f,-1.0f);
            }
        #pragma unroll
        for (int g = 0; g < 8; ++g)
            #pragma unroll
            for (int s = 0; s < 2; ++s)
                CMULBF(zr[s][g*2],zi[s][g*2],zr[s][g*2+1],zi[s][g*2+1],1.0f,0.0f);
    }

    // ---- Phase 3: twiddle W1024^{lane*k1}; one chain, applied to both streams
    {
        constexpr int BREV4[16] = {0,8,4,12,2,10,6,14,1,9,5,13,3,11,7,15};
        float s1, c1;
        __sincosf((float)lane * (-6.283185307179586f / 1024.0f), &s1, &c1);
        float cwr = c1, cwi = s1;
        #pragma unroll
        for (int k1 = 1; k1 < 16; ++k1) {
            const int r = BREV4[k1];
            #pragma unroll
            for (int s = 0; s < 2; ++s) {
                float tr; CMUL(zr[s][r],zi[s][r],cwr,cwi,tr,zi[s][r]);
                zr[s][r] = tr;
            }
            if (k1 < 15) { float nr; CMUL(cwr,cwi,c1,s1,nr,cwi); cwr = nr; }
        }
    }

    // ---- Phase 4: 64-point DIF FFT across lanes; stage sincos shared
    #pragma unroll
    for (int st = 0; st < 6; ++st) {
        const int half = 32 >> st;
        const int j = lane & (half - 1);
        float sw = 0.0f, cw = 1.0f;
        if (half > 1)
            __sincosf((float)j * (-6.283185307179586f / (float)(2 * half)), &sw, &cw);
        const bool hi = (lane & half) != 0;
        #pragma unroll
        for (int r = 0; r < 16; ++r)
            #pragma unroll
            for (int s = 0; s < 2; ++s) {
                float prr = __shfl_xor(zr[s][r], half);
                float pii = __shfl_xor(zi[s][r], half);
                float sr = zr[s][r] + prr, si = zi[s][r] + pii;
                float dr = prr - zr[s][r], di = pii - zi[s][r];
                float tr = dr * cw - di * sw, ti = dr * sw + di * cw;
                zr[s][r] = hi ? tr : sr;
                zi[s][r] = hi ? ti : si;
            }
    }

    // ---- Phase 5: 4 dump/unpack passes, two alternating buffers
    const int K2 = (int)(__brev((unsigned)lane) >> 26);   // brev6(lane)
    const int dbase = 17 * K2;
    constexpr int BREV4[16] = {0,8,4,12,2,10,6,14,1,9,5,13,3,11,7,15};
    const size_t obase = (((size_t)b * NW + w) * NC + cbase) * NBINS;

    // dump0 <- A.re
    #pragma unroll
    for (int r = 0; r < 16; ++r) dump0[dbase + BREV4[r]] = zr[0][r];
    __builtin_amdgcn_wave_barrier();
    // unpack A.re -> chirp cbase+0 ; dump1 <- A.im
    #pragma unroll
    for (int r = 0; r < 16; ++r) dump1[dbase + BREV4[r]] = zi[0][r];
    #pragma unroll
    for (int t = 0; t < 9; ++t) {
        int k = lane + (t << 6);
        if (k < NBINS) {
            int rk = (KLEN - k) & (KLEN - 1);
            out[obase + k] = 0.5f * (dump0[DIDX(k)] + dump0[DIDX(rk)]);
        }
    }
    __builtin_amdgcn_wave_barrier();
    // unpack A.im -> chirp cbase+1 ; dump0 <- B.re
    #pragma unroll
    for (int r = 0; r < 16; ++r) dump0[dbase + BREV4[r]] = zr[1][r];
    #pragma unroll
    for (int t = 0; t < 9; ++t) {
        int k = lane + (t << 6);
        if (k < NBINS) {
            int rk = (KLEN - k) & (KLEN - 1);
            out[obase + NBINS + k] = 0.5f * (dump1[DIDX(k)] + dump1[DIDX(rk)]);
        }
    }
    __builtin_amdgcn_wave_barrier();
    // unpack B.re -> chirp cbase+2 ; dump1 <- B.im
    #pragma unroll
    for (int r = 0; r < 16; ++r) dump1[dbase + BREV4[r]] = zi[1][r];
    #pragma unroll
    for (int t = 0; t < 9; ++t) {
        int k = lane + (t << 6);
        if (k < NBINS) {
            int rk = (KLEN - k) & (KLEN - 1);
            out[obase + 2 * NBINS + k] = 0.5f * (dump0[DIDX(k)] + dump0[DIDX(rk)]);
        }
    }
    __builtin_amdgcn_wave_barrier();
    // unpack B.im -> chirp cbase+3
    #pragma unroll
    for (int t = 0; t < 9; ++t) {
        int k = lane + (t << 6);
        if (k < NBINS) {
            int rk = (KLEN - k) & (KLEN - 1);
            out[obase + 3 * NBINS + k] = 0.5f * (dump1[DIDX(k)] + dump1[DIDX(rk)]);
        }
    }
}

extern "C" void kernel_launch(void* const* d_in, const int* in_sizes, int n_in,
                              void* d_out, int out_size, void* d_ws, size_t ws_size,
                              hipStream_t stream) {
    const float* x = nullptr;
    const float* dlnf = nullptr;
    for (int i = 0; i < n_in; ++i) {
        if (in_sizes[i] == NB * NSAMP)      x = (const float*)d_in[i];
        else if (in_sizes[i] == NC)         dlnf = (const float*)d_in[i];
    }
    if (!x)    x    = (const float*)d_in[0];
    if (!dlnf) dlnf = (const float*)d_in[1];
    float* out = (float*)d_out;

    char* ws = (char*)d_ws;
    float4* map    = (float4*)ws;
    float*  g_hann = (float*)(ws + WS_HANN);

    warpmap_kernel<<<NC, 256, 0, stream>>>(dlnf, map, g_hann);

    const int nblocks = NB * NW * 4;  // 8176 one-wave blocks, 2 chirp-pairs each
    dechirp_regfft2_kernel<<<nblocks, 64, 0, stream>>>(x, map, (const float4*)g_hann, out);
}

// Round 28
// 59.345 us; speedup vs baseline: 1.8216x; 1.8216x over previous
//
#include <hip/hip_runtime.h>

#define KLEN 1024
#define HOP 512
#define NW 511
#define NB 4
#define NC 16
#define NBINS 513
#define NSAMP 262144
#define MAPN (NC * KLEN)

// ws layout (bytes): map float4[MAPN] @0 | hann float[1024] @262144
#define WS_HANN 262144

// Bank-XOR swizzle: bijective in every 32-float segment; all FFT strides <=2-way.
#define SWZ(i) (((i) & ~31) | (((i) ^ ((i) >> 5) ^ ((i) >> 10)) & 31))

__global__ __launch_bounds__(256) void warpmap_kernel(
    const float* __restrict__ dlnf,
    float4* __restrict__ map, float* __restrict__ g_hann)
{
    const int c = blockIdx.x;
    const double TWO_PI = 6.283185307179586476925287;
    const double beta = 2.0 * (double)dlnf[c];
    const bool small = fabs(beta) < 1e-8;
    const double bs = small ? 1e-8 : beta;
    const double e2b = exp(2.0 * bs);
    const double t_mid = small ? 0.0 : (log(1.0 + 0.5 * (e2b - 1.0)) / bs - 1.0);

    for (int j = threadIdx.x; j < KLEN; j += 256) {
        double tau = 2.0 * (double)j / 1024.0 - 1.0;
        double ts, jac;
        if (small) { ts = tau; jac = 1.0; }
        else {
            ts = log(1.0 + (tau + 1.0) * 0.5 * (e2b - 1.0)) / bs - 1.0;
            jac = exp(-bs * (ts - t_mid));
        }
        double idxf = 512.0 * (ts + 1.0);
        int lo = (int)idxf;
        lo = lo < 0 ? 0 : (lo > 1022 ? 1022 : lo);
        map[c * KLEN + j] = make_float4(__int_as_float(lo),
                                        (float)(idxf - (double)lo),
                                        (float)jac, 0.0f);
    }
    if (c == 0) {
        for (int k = threadIdx.x; k < KLEN; k += 256)
            g_hann[k] = (float)(0.5 * (1.0 - cos(TWO_PI * (double)k / 1024.0)));
    }
}

__global__ __launch_bounds__(256) void dechirp_fftg_kernel(
    const float* __restrict__ x,
    const float4* __restrict__ map,
    const float* __restrict__ g_hann,
    float* __restrict__ out)
{
    __shared__ float2 wd2[KLEN];                 // (v[k], v[k+1]) pairs, 8 KB
    __shared__ float reA[4][KLEN], imA[4][KLEN]; // 32 KB

    const int tid  = threadIdx.x;
    const int lane = tid & 63;
    const int wv   = tid >> 6;
    const int blin = blockIdx.x;            // (b*NW + w)*2 + half
    const int hlf  = blin & 1;
    const int w    = (blin >> 1) % NW;
    const int b    = blin / (2 * NW);
    const int q    = hlf * 4 + wv;          // chirp pair of this wave
    const int c0 = 2 * q, c1 = 2 * q + 1;

    // Build windowed pair table (one barrier total)
    const float* xrow = x + (size_t)b * NSAMP + (size_t)w * HOP;
    {
        const int k4 = tid << 2;            // 0..1020
        float4 xv = *(const float4*)(xrow + k4);
        float4 hv = *(const float4*)(g_hann + k4);
        float v0 = xv.x * hv.x, v1 = xv.y * hv.y, v2 = xv.z * hv.z, v3 = xv.w * hv.w;
        int k5 = k4 + 4; if (k5 > 1023) k5 = 1023;
        float v4 = xrow[k5] * g_hann[k5];
        wd2[k4 + 0] = make_float2(v0, v1);
        wd2[k4 + 1] = make_float2(v1, v2);
        wd2[k4 + 2] = make_float2(v2, v3);
        wd2[k4 + 3] = make_float2(v3, v4);
    }
    __syncthreads();

    float* re = reA[wv];
    float* im = imA[wv];
    const float4* m0 = map + c0 * KLEN;
    const float4* m1 = map + c1 * KLEN;

    // Fused resample + FIRST double-stage (s=0: twiddles are 1 and -i).
    // Slots {4m..4m+3} (m = brev8(j0)) hold natural samples {j0, j0+512, j0+256, j0+768}.
    #pragma unroll
    for (int g = 0; g < 4; ++g) {
        const int j0 = lane + (g << 6);     // coalesced map loads across lanes
        float zr[4], zi[4];
        #pragma unroll
        for (int d = 0; d < 4; ++d) {
            constexpr int OFF[4] = {0, 512, 256, 768};
            int j = j0 + OFF[d];
            float4 a = m0[j];
            int a0 = __float_as_int(a.x);
            float2 p = wd2[a0];
            zr[d] = (p.x * (1.0f - a.y) + p.y * a.y) * a.z;
            float4 bq = m1[j];
            int a1 = __float_as_int(bq.x);
            float2 pp = wd2[a1];
            zi[d] = (pp.x * (1.0f - bq.y) + pp.y * bq.y) * bq.z;
        }
        // radix-4 butterfly with wA=1, wB0=1, wB1=-i (exact)
        float b0r = zr[0] + zr[1], b0i = zi[0] + zi[1];
        float b1r = zr[0] - zr[1], b1i = zi[0] - zi[1];
        float b2r = zr[2] + zr[3], b2i = zi[2] + zi[3];
        float b3r = zr[2] - zr[3], b3i = zi[2] - zi[3];
        const int base = ((int)(__brev((unsigned)j0) >> 24)) << 2;
        re[SWZ(base + 0)] = b0r + b2r;  im[SWZ(base + 0)] = b0i + b2i;
        re[SWZ(base + 2)] = b0r - b2r;  im[SWZ(base + 2)] = b0i - b2i;
        re[SWZ(base + 1)] = b1r + b3i;  im[SWZ(base + 1)] = b1i - b3r;
        re[SWZ(base + 3)] = b1r - b3i;  im[SWZ(base + 3)] = b1i + b3r;
    }
    __builtin_amdgcn_wave_barrier();

    // Remaining 4 double-stages (s = 2,4,6,8), wave-synchronous, sincos twiddles
    #pragma unroll
    for (int s = 2; s <= 8; s += 2) {
        const int h = 1 << s;
        #pragma unroll
        for (int g = 0; g < 4; ++g) {
            const int m = lane + (g << 6);          // group id 0..255
            const int j = m & (h - 1);
            const int base = ((m >> s) << (s + 2)) | j;
            const int i0 = SWZ(base), i1 = SWZ(base + h);
            const int i2 = SWZ(base + 2 * h), i3 = SWZ(base + 3 * h);

            float ar0 = re[i0], ai0 = im[i0];
            float ar1 = re[i1], ai1 = im[i1];
            float ar2 = re[i2], ai2 = im[i2];
            float ar3 = re[i3], ai3 = im[i3];

            float ang = (float)(j << (8 - s)) * (-6.283185307179586f / 1024.0f);
            float sn, cs;
            __sincosf(ang, &sn, &cs);
            float wB0x = cs,                wB0y = sn;              // W^e
            float wAx  = cs * cs - sn * sn, wAy  = 2.0f * cs * sn;  // W^{2e}
            float wB1x = sn,                wB1y = -cs;             // W^{e+256}

            float v1r = ar1 * wAx - ai1 * wAy, v1i = ar1 * wAy + ai1 * wAx;
            float b0r = ar0 + v1r, b0i = ai0 + v1i;
            float b1r = ar0 - v1r, b1i = ai0 - v1i;
            float v3r = ar3 * wAx - ai3 * wAy, v3i = ar3 * wAy + ai3 * wAx;
            float b2r = ar2 + v3r, b2i = ai2 + v3i;
            float b3r = ar2 - v3r, b3i = ai2 - v3i;

            float v2r = b2r * wB0x - b2i * wB0y, v2i = b2r * wB0y + b2i * wB0x;
            float v3br = b3r * wB1x - b3i * wB1y, v3bi = b3r * wB1y + b3i * wB1x;

            re[i0] = b0r + v2r;  im[i0] = b0i + v2i;
            re[i2] = b0r - v2r;  im[i2] = b0i - v2i;
            re[i1] = b1r + v3br; im[i1] = b1i + v3bi;
            re[i3] = b1r - v3br; im[i3] = b1i - v3bi;
        }
        __builtin_amdgcn_wave_barrier();
    }

    // Unpack real parts: Re F_k = (re[k]+re[N-k])/2 ; Re G_k = (im[k]+im[N-k])/2
    size_t obase0 = (((size_t)b * NW + w) * NC + c0) * NBINS;
    size_t obase1 = obase0 + NBINS;
    #pragma unroll
    for (int t = 0; t < 9; ++t) {
        int k = lane + (t << 6);
        if (k < NBINS) {
            int rk = (KLEN - k) & (KLEN - 1);
            float fr = 0.5f * (re[SWZ(k)] + re[SWZ(rk)]);
            float gr = 0.5f * (im[SWZ(k)] + im[SWZ(rk)]);
            out[obase0 + k] = fr;
            out[obase1 + k] = gr;
        }
    }
}

extern "C" void kernel_launch(void* const* d_in, const int* in_sizes, int n_in,
                              void* d_out, int out_size, void* d_ws, size_t ws_size,
                              hipStream_t stream) {
    const float* x = nullptr;
    const float* dlnf = nullptr;
    for (int i = 0; i < n_in; ++i) {
        if (in_sizes[i] == NB * NSAMP)      x = (const float*)d_in[i];
        else if (in_sizes[i] == NC)         dlnf = (const float*)d_in[i];
    }
    if (!x)    x    = (const float*)d_in[0];
    if (!dlnf) dlnf = (const float*)d_in[1];
    float* out = (float*)d_out;

    char* ws = (char*)d_ws;
    float4* map    = (float4*)ws;
    float*  g_hann = (float*)(ws + WS_HANN);

    warpmap_kernel<<<NC, 256, 0, stream>>>(dlnf, map, g_hann);

    const int nblocks = NB * NW * 2;  // 4088 blocks, 4 waves, 1 chirp-pair per wave
    dechirp_fftg_kernel<<<nblocks, 256, 0, stream>>>(x, map, g_hann, out);
}

// Round 29
// 46.932 us; speedup vs baseline: 2.3034x; 1.2645x over previous
//
#include <hip/hip_runtime.h>

#define KLEN 1024
#define HOP 512
#define NW 511
#define NB 4
#define NC 16
#define NBINS 513
#define NSAMP 262144
#define MAPN (NC * KLEN)

// ws layout (bytes): map float4[MAPN] @0 | hann float[1024] @262144
#define WS_HANN 262144

// Bank-XOR swizzle: bijective in every 32-float segment; all strides <=2-way.
#define SWZ(i) (((i) & ~31) | (((i) ^ ((i) >> 5) ^ ((i) >> 10)) & 31))

// DIT butterfly: T = b*w; b = a - T; a = a + T
#define DITBF(ar,ai,br,bi,wr,wi) { float tr_=(br)*(wr)-(bi)*(wi), ti_=(br)*(wi)+(bi)*(wr); \
    (br)=(ar)-tr_; (bi)=(ai)-ti_; (ar)+=tr_; (ai)+=ti_; }
#define CMUL(xr,xi,yr,yi,or_,oi_) { (or_)=(xr)*(yr)-(xi)*(yi); (oi_)=(xr)*(yi)+(xi)*(yr); }

__global__ __launch_bounds__(256) void warpmap_kernel(
    const float* __restrict__ dlnf,
    float4* __restrict__ map, float* __restrict__ g_hann)
{
    const int c = blockIdx.x;
    const double TWO_PI = 6.283185307179586476925287;
    const double beta = 2.0 * (double)dlnf[c];
    const bool small = fabs(beta) < 1e-8;
    const double bs = small ? 1e-8 : beta;
    const double e2b = exp(2.0 * bs);
    const double t_mid = small ? 0.0 : (log(1.0 + 0.5 * (e2b - 1.0)) / bs - 1.0);

    for (int j = threadIdx.x; j < KLEN; j += 256) {
        double tau = 2.0 * (double)j / 1024.0 - 1.0;
        double ts, jac;
        if (small) { ts = tau; jac = 1.0; }
        else {
            ts = log(1.0 + (tau + 1.0) * 0.5 * (e2b - 1.0)) / bs - 1.0;
            jac = exp(-bs * (ts - t_mid));
        }
        double idxf = 512.0 * (ts + 1.0);
        int lo = (int)idxf;
        lo = lo < 0 ? 0 : (lo > 1022 ? 1022 : lo);
        map[c * KLEN + j] = make_float4(__int_as_float(lo),
                                        (float)(idxf - (double)lo),
                                        (float)jac, 0.0f);
    }
    if (c == 0) {
        for (int k = threadIdx.x; k < KLEN; k += 256)
            g_hann[k] = (float)(0.5 * (1.0 - cos(TWO_PI * (double)k / 1024.0)));
    }
}

// 4 in-register DIT stages on a 16-point group; u = W_1024^(j0 * 2^(6-s))
__device__ __forceinline__ void fft16_dit(float* vr, float* vi, float uc, float us)
{
    float u2r, u2i, u4r, u4i, u8r, u8i;
    CMUL(uc, us, uc, us, u2r, u2i);
    CMUL(u2r, u2i, u2r, u2i, u4r, u4i);
    CMUL(u4r, u4i, u4r, u4i, u8r, u8i);

    // stage s: pairs (2i, 2i+1), twiddle u^8
    #pragma unroll
    for (int i = 0; i < 8; ++i)
        DITBF(vr[2*i], vi[2*i], vr[2*i+1], vi[2*i+1], u8r, u8i);

    // stage s+1: pairs (t, t+2), t&2==0; twiddle u^4 * (-i)^(t&1)
    #pragma unroll
    for (int i = 0; i < 4; ++i) {
        int t0 = (i >> 1) * 8 + (i & 1) * 4;   // 0,4,8,12
        DITBF(vr[t0],   vi[t0],   vr[t0+2], vi[t0+2], u4r, u4i);
        DITBF(vr[t0+1], vi[t0+1], vr[t0+3], vi[t0+3], u4i, -u4r);
    }

    // stage s+2: pairs (t, t+4), t&4==0; twiddle u^2 * W8^(t&3)
    {
        const float R2 = 0.70710678118654752f;
        float w1r, w1i, w3r, w3i;
        CMUL(u2r, u2i,  R2, -R2, w1r, w1i);
        CMUL(u2r, u2i, -R2, -R2, w3r, w3i);
        #pragma unroll
        for (int g = 0; g < 2; ++g) {
            int t0 = g * 8;
            DITBF(vr[t0],   vi[t0],   vr[t0+4], vi[t0+4], u2r, u2i);
            DITBF(vr[t0+1], vi[t0+1], vr[t0+5], vi[t0+5], w1r, w1i);
            DITBF(vr[t0+2], vi[t0+2], vr[t0+6], vi[t0+6], u2i, -u2r);
            DITBF(vr[t0+3], vi[t0+3], vr[t0+7], vi[t0+7], w3r, w3i);
        }
    }

    // stage s+3: pairs (t, t+8); twiddle u * W16^t
    {
        constexpr float W16R[8] = { 1.0f, 0.92387953251f, 0.70710678119f, 0.38268343236f,
                                    0.0f,-0.38268343236f,-0.70710678119f,-0.92387953251f };
        constexpr float W16I[8] = { 0.0f,-0.38268343236f,-0.70710678119f,-0.92387953251f,
                                   -1.0f,-0.92387953251f,-0.70710678119f,-0.38268343236f };
        #pragma unroll
        for (int t = 0; t < 8; ++t) {
            float wr, wi;
            CMUL(uc, us, W16R[t], W16I[t], wr, wi);
            DITBF(vr[t], vi[t], vr[t+8], vi[t+8], wr, wi);
        }
    }
}

__global__ __launch_bounds__(256) void dechirp_fft16_kernel(
    const float* __restrict__ x,
    const float4* __restrict__ map,
    const float* __restrict__ g_hann,
    float* __restrict__ out)
{
    __shared__ float2 wd2[KLEN];                 // (v[k], v[k+1]) pairs, 8 KB
    __shared__ float reA[4][KLEN], imA[4][KLEN]; // 32 KB

    const int tid  = threadIdx.x;
    const int lane = tid & 63;
    const int wv   = tid >> 6;
    const int blin = blockIdx.x;            // (b*NW + w)*2 + half
    const int hlf  = blin & 1;
    const int w    = (blin >> 1) % NW;
    const int b    = blin / (2 * NW);
    const int q    = hlf * 4 + wv;          // chirp pair of this wave
    const int c0 = 2 * q, c1 = 2 * q + 1;

    // Build windowed pair table (one block barrier total)
    const float* xrow = x + (size_t)b * NSAMP + (size_t)w * HOP;
    {
        const int k4 = tid << 2;            // 0..1020
        float4 xv = *(const float4*)(xrow + k4);
        float4 hv = *(const float4*)(g_hann + k4);
        float v0 = xv.x * hv.x, v1 = xv.y * hv.y, v2 = xv.z * hv.z, v3 = xv.w * hv.w;
        int k5 = k4 + 4; if (k5 > 1023) k5 = 1023;
        float v4 = xrow[k5] * g_hann[k5];
        wd2[k4 + 0] = make_float2(v0, v1);
        wd2[k4 + 1] = make_float2(v1, v2);
        wd2[k4 + 2] = make_float2(v2, v3);
        wd2[k4 + 3] = make_float2(v3, v4);
    }
    __syncthreads();

    float* re = reA[wv];
    float* im = imA[wv];
    const float4* m0 = map + c0 * KLEN;
    const float4* m1 = map + c1 * KLEN;

    // Fused resample + stages 0,1 (twiddles 1 and -i, exact).
    // Slots {4m..4m+3} (m = brev8(j0)) hold samples {j0, j0+512, j0+256, j0+768}.
    #pragma unroll
    for (int g = 0; g < 4; ++g) {
        const int j0 = lane + (g << 6);     // coalesced map loads
        float zr[4], zi[4];
        #pragma unroll
        for (int d = 0; d < 4; ++d) {
            constexpr int OFF[4] = {0, 512, 256, 768};
            int j = j0 + OFF[d];
            float4 a = m0[j];
            int a0 = __float_as_int(a.x);
            float2 p = wd2[a0];
            zr[d] = (p.x * (1.0f - a.y) + p.y * a.y) * a.z;
            float4 bq = m1[j];
            int a1 = __float_as_int(bq.x);
            float2 pp = wd2[a1];
            zi[d] = (pp.x * (1.0f - bq.y) + pp.y * bq.y) * bq.z;
        }
        float b0r = zr[0] + zr[1], b0i = zi[0] + zi[1];
        float b1r = zr[0] - zr[1], b1i = zi[0] - zi[1];
        float b2r = zr[2] + zr[3], b2i = zi[2] + zi[3];
        float b3r = zr[2] - zr[3], b3i = zi[2] - zi[3];
        const int base = ((int)(__brev((unsigned)j0) >> 24)) << 2;
        re[SWZ(base + 0)] = b0r + b2r;  im[SWZ(base + 0)] = b0i + b2i;
        re[SWZ(base + 2)] = b0r - b2r;  im[SWZ(base + 2)] = b0i - b2i;
        re[SWZ(base + 1)] = b1r + b3i;  im[SWZ(base + 1)] = b1i - b3r;
        re[SWZ(base + 3)] = b1r - b3i;  im[SWZ(base + 3)] = b1i + b3r;
    }
    __builtin_amdgcn_wave_barrier();

    // Pass A: radix-16 over stages 2..5. Group m=lane: slots base + 4t.
    {
        float vr[16], vi[16];
        const int j0 = lane & 3;
        const int base = ((lane >> 2) << 6) | j0;
        #pragma unroll
        for (int t = 0; t < 16; ++t) {
            int idx = SWZ(base + (t << 2));
            vr[t] = re[idx]; vi[t] = im[idx];
        }
        float uc, us;   // u = W^(16*j0)
        __sincosf((float)(j0 << 4) * (-6.283185307179586f / 1024.0f), &us, &uc);
        fft16_dit(vr, vi, uc, us);
        #pragma unroll
        for (int t = 0; t < 16; ++t) {
            int idx = SWZ(base + (t << 2));
            re[idx] = vr[t]; im[idx] = vi[t];
        }
    }
    __builtin_amdgcn_wave_barrier();

    // Pass B: radix-16 over stages 6..9. Group = lane: slots lane + 64t.
    float vr[16], vi[16];
    {
        #pragma unroll
        for (int t = 0; t < 16; ++t) {
            int idx = SWZ(lane + (t << 6));
            vr[t] = re[idx]; vi[t] = im[idx];
        }
        float uc, us;   // u = W^lane
        __sincosf((float)lane * (-6.283185307179586f / 1024.0f), &us, &uc);
        fft16_dit(vr, vi, uc, us);
        // vr/vi[t] = Z[lane + 64 t]  (natural order)
    }

    // Shfl unpack: partner of bin k=l+64t is lane 64-l, reg 15-t (lane 0: self, reg (16-t)&15)
    size_t obase0 = (((size_t)b * NW + w) * NC + c0) * NBINS;
    size_t obase1 = obase0 + NBINS;
    const int src = (64 - lane) & 63;
    #pragma unroll
    for (int t = 0; t < 8; ++t) {
        float pr = __shfl(vr[15 - t], src);
        float pi = __shfl(vi[15 - t], src);
        if (lane == 0) { pr = vr[(16 - t) & 15]; pi = vi[(16 - t) & 15]; }
        int k = lane + (t << 6);
        out[obase0 + k] = 0.5f * (vr[t] + pr);
        out[obase1 + k] = 0.5f * (vi[t] + pi);
    }
    if (lane == 0) {
        out[obase0 + 512] = vr[8];
        out[obase1 + 512] = vi[8];
    }
}

extern "C" void kernel_launch(void* const* d_in, const int* in_sizes, int n_in,
                              void* d_out, int out_size, void* d_ws, size_t ws_size,
                              hipStream_t stream) {
    const float* x = nullptr;
    const float* dlnf = nullptr;
    for (int i = 0; i < n_in; ++i) {
        if (in_sizes[i] == NB * NSAMP)      x = (const float*)d_in[i];
        else if (in_sizes[i] == NC)         dlnf = (const float*)d_in[i];
    }
    if (!x)    x    = (const float*)d_in[0];
    if (!dlnf) dlnf = (const float*)d_in[1];
    float* out = (float*)d_out;

    char* ws = (char*)d_ws;
    float4* map    = (float4*)ws;
    float*  g_hann = (float*)(ws + WS_HANN);

    warpmap_kernel<<<NC, 256, 0, stream>>>(dlnf, map, g_hann);

    const int nblocks = NB * NW * 2;  // 4088 blocks, 4 waves, 1 chirp-pair per wave
    dechirp_fft16_kernel<<<nblocks, 256, 0, stream>>>(x, map, g_hann, out);
}